// Round 1
// baseline (39.616 us; speedup 1.0000x reference)
//
#include <hip/hip_runtime.h>
#include <math.h>

// BBoxEstimatorLoss: fused per-sample loss + deterministic 2-stage reduction.
// BS = 524288 samples, exact grid 2048 blocks x 256 threads (1 sample/thread).

constexpr int BS_N  = 524288;
constexpr int NBLK  = 2048;   // 2048 * 256 == BS_N

__constant__ float G_MEAN[8][3] = {
    {3.88f, 1.63f, 1.53f}, {0.84f, 0.66f, 1.76f}, {1.76f, 0.60f, 1.74f},
    {16.17f, 2.58f, 3.23f}, {3.90f, 1.60f, 1.56f}, {1.73f, 0.58f, 1.37f},
    {0.91f, 0.48f, 1.78f}, {2.06f, 1.86f, 1.66f}
};

// huber(a, delta) for a >= 0:  a<=d ? 0.5 a^2 : d*(a - 0.5 d)
__device__ __forceinline__ float huber_pos(float a, float delta) {
    return (a <= delta) ? 0.5f * a * a : delta * (a - 0.5f * delta);
}
// huber(sqrt(d2), delta) without sqrt in the common branch
__device__ __forceinline__ float huber_norm2(float d2, float delta) {
    return (d2 <= delta * delta) ? 0.5f * d2
                                 : delta * (sqrtf(d2) - 0.5f * delta);
}

__global__ __launch_bounds__(256) void bbox_partial(
    const float* __restrict__ center,
    const float* __restrict__ center_label,
    const float* __restrict__ stage1_center,
    const float* __restrict__ heading_scores,
    const float* __restrict__ hrn,          // heading_residuals_normalized
    const float* __restrict__ hres,         // heading_residuals
    const int*   __restrict__ hcls_in,
    const float* __restrict__ hres_label,
    const float* __restrict__ size_scores,
    const float* __restrict__ srn,          // size_residuals_normalized (BS,8,3)
    const float* __restrict__ sres,         // size_residuals (BS,8,3)
    const int*   __restrict__ scls_in,
    const float* __restrict__ sres_label,   // (BS,3)
    float* __restrict__ block_out)
{
    const int i = blockIdx.x * 256 + threadIdx.x;

    float contrib = 0.0f;

    const int h = hcls_in[i];
    const int s = scls_in[i];

    // ---- centers ----
    const float cx = center[3*i+0], cy = center[3*i+1], cz = center[3*i+2];
    const float lx = center_label[3*i+0], ly = center_label[3*i+1], lz = center_label[3*i+2];

    const float dx0 = cx - lx, dy0 = cy - ly, dz0 = cz - lz;
    contrib += huber_norm2(dx0*dx0 + dy0*dy0 + dz0*dz0, 2.0f);     // center_loss
    {
        const float ax = cx - stage1_center[3*i+0];
        const float ay = cy - stage1_center[3*i+1];
        const float az = cz - stage1_center[3*i+2];
        contrib += huber_norm2(ax*ax + ay*ay + az*az, 1.0f);       // stage1_center_loss
    }

    // ---- heading log-softmax (12) ----
    {
        const float4* p = reinterpret_cast<const float4*>(heading_scores + 12*i); // 48B-aligned
        const float4 a = p[0], b = p[1], c4 = p[2];
        float m = fmaxf(fmaxf(fmaxf(a.x,a.y),fmaxf(a.z,a.w)),
                  fmaxf(fmaxf(fmaxf(b.x,b.y),fmaxf(b.z,b.w)),
                        fmaxf(fmaxf(c4.x,c4.y),fmaxf(c4.z,c4.w))));
        float se = __expf(a.x-m)+__expf(a.y-m)+__expf(a.z-m)+__expf(a.w-m)
                 + __expf(b.x-m)+__expf(b.y-m)+__expf(b.z-m)+__expf(b.w-m)
                 + __expf(c4.x-m)+__expf(c4.y-m)+__expf(c4.z-m)+__expf(c4.w-m);
        const float lse = m + __logf(se);
        contrib += lse - heading_scores[12*i + h];                 // heading_class_loss
    }

    // ---- size log-softmax (8) ----
    {
        const float4* p = reinterpret_cast<const float4*>(size_scores + 8*i); // 32B-aligned
        const float4 a = p[0], b = p[1];
        float m = fmaxf(fmaxf(fmaxf(a.x,a.y),fmaxf(a.z,a.w)),
                        fmaxf(fmaxf(b.x,b.y),fmaxf(b.z,b.w)));
        float se = __expf(a.x-m)+__expf(a.y-m)+__expf(a.z-m)+__expf(a.w-m)
                 + __expf(b.x-m)+__expf(b.y-m)+__expf(b.z-m)+__expf(b.w-m);
        const float lse = m + __logf(se);
        contrib += lse - size_scores[8*i + s];                     // size_class_loss
    }

    const float hrl = hres_label[i];

    // ---- heading residual loss (x20) ----
    {
        const float pred = hrn[12*i + h];
        const float labn = hrl * (float)(12.0 / M_PI);             // / (pi/12)
        contrib += 20.0f * huber_pos(fabsf(pred - labn), 1.0f);
    }

    // ---- size residual loss (x20) ----
    const float m0 = G_MEAN[s][0], m1 = G_MEAN[s][1], m2c = G_MEAN[s][2];
    const int   sb = (8*i + s) * 3;
    const float sl0 = sres_label[3*i+0], sl1 = sres_label[3*i+1], sl2 = sres_label[3*i+2];
    {
        const float e0 = sl0 / m0 - srn[sb+0];
        const float e1 = sl1 / m1 - srn[sb+1];
        const float e2 = sl2 / m2c - srn[sb+2];
        contrib += 20.0f * huber_norm2(e0*e0 + e1*e1 + e2*e2, 1.0f);
    }

    // ---- corner loss (x10, mean over 8 corners) ----
    {
        const float binc = (float)h * (float)(M_PI / 6.0);
        const float hp = hres[12*i + h] + binc;                    // heading_pred
        const float hg = hrl + binc;                               // heading_label
        const float lp2 = 0.5f * (m0 + sres[sb+0]);                // 0.5 * l_pred
        const float wp2 = 0.5f * (m1 + sres[sb+1]);                // 0.5 * w_pred
        const float hp2 = 0.5f * (m2c + sres[sb+2]);               // 0.5 * h_pred
        const float lg2 = 0.5f * (m0 + sl0);
        const float wg2 = 0.5f * (m1 + sl1);
        const float hg2 = 0.5f * (m2c + sl2);
        float cp, sp, cg, sg;
        __sincosf(hp, &sp, &cp);
        __sincosf(hg, &sg, &cg);
        const float dyh = hp2 - hg2;

        // flip (heading+pi) corners are sign-negated rotated offsets of gt.
        constexpr float SX[8] = {1,1,-1,-1,1,1,-1,-1};
        constexpr float SY[8] = {1,1,1,1,-1,-1,-1,-1};
        constexpr float SZ[8] = {1,-1,-1,1,1,-1,-1,1};
        float csum = 0.0f;
        #pragma unroll
        for (int j = 0; j < 8; ++j) {
            const float axp = SX[j]*lp2, azp = SZ[j]*wp2;
            const float xrp = cp*axp + sp*azp;
            const float zrp = cp*azp - sp*axp;
            const float axg = SX[j]*lg2, azg = SZ[j]*wg2;
            const float xrg = cg*axg + sg*azg;
            const float zrg = cg*azg - sg*axg;
            const float ddy = dy0 + SY[j]*dyh;
            const float u = dx0 + xrp, v = dz0 + zrp;
            const float du1 = u - xrg, dv1 = v - zrg;   // vs gt
            const float du2 = u + xrg, dv2 = v + zrg;   // vs gt_flip
            const float y2 = ddy*ddy;
            const float dgt = du1*du1 + y2 + dv1*dv1;
            const float dfl = du2*du2 + y2 + dv2*dv2;
            const float mm = fminf(dgt, dfl);
            csum += (mm <= 1.0f) ? 0.5f*mm : sqrtf(mm) - 0.5f;
        }
        contrib += 1.25f * csum;   // 10.0 * (1/8)
    }

    // ---- deterministic block reduction ----
    #pragma unroll
    for (int off = 32; off > 0; off >>= 1)
        contrib += __shfl_down(contrib, off, 64);

    __shared__ float sdata[4];
    const int lane = threadIdx.x & 63;
    const int wid  = threadIdx.x >> 6;
    if (lane == 0) sdata[wid] = contrib;
    __syncthreads();
    if (threadIdx.x == 0)
        block_out[blockIdx.x] = (sdata[0] + sdata[1]) + (sdata[2] + sdata[3]);
}

__global__ __launch_bounds__(256) void bbox_final(
    const float* __restrict__ block_in, float* __restrict__ out)
{
    float ssum = 0.0f;
    for (int i = threadIdx.x; i < NBLK; i += 256)
        ssum += block_in[i];
    #pragma unroll
    for (int off = 32; off > 0; off >>= 1)
        ssum += __shfl_down(ssum, off, 64);

    __shared__ float sdata[4];
    const int lane = threadIdx.x & 63;
    const int wid  = threadIdx.x >> 6;
    if (lane == 0) sdata[wid] = ssum;
    __syncthreads();
    if (threadIdx.x == 0)
        out[0] = ((sdata[0] + sdata[1]) + (sdata[2] + sdata[3])) * (1.0f / (float)BS_N);
}

extern "C" void kernel_launch(void* const* d_in, const int* in_sizes, int n_in,
                              void* d_out, int out_size, void* d_ws, size_t ws_size,
                              hipStream_t stream) {
    const float* center        = (const float*)d_in[0];
    const float* center_label  = (const float*)d_in[1];
    const float* stage1_center = (const float*)d_in[2];
    const float* heading_sc    = (const float*)d_in[3];
    const float* hrn           = (const float*)d_in[4];
    const float* hres          = (const float*)d_in[5];
    const int*   hcls          = (const int*)d_in[6];
    const float* hres_label    = (const float*)d_in[7];
    const float* size_sc       = (const float*)d_in[8];
    const float* srn           = (const float*)d_in[9];
    const float* sres          = (const float*)d_in[10];
    const int*   scls          = (const int*)d_in[11];
    const float* sres_label    = (const float*)d_in[12];

    float* ws  = (float*)d_ws;     // NBLK partial sums (8 KiB)
    float* out = (float*)d_out;

    bbox_partial<<<NBLK, 256, 0, stream>>>(
        center, center_label, stage1_center, heading_sc, hrn, hres,
        hcls, hres_label, size_sc, srn, sres, scls, sres_label, ws);
    bbox_final<<<1, 256, 0, stream>>>(ws, out);
}